// Round 9
// baseline (360.994 us; speedup 1.0000x reference)
//
#include <hip/hip_runtime.h>

// SSIM loss, streaming-row kernel, no LDS in the hot loop, no barriers.
// History: r5-r9 1-col @ budget-128 -> AGPR/scratch spill, 203us. r10 (2,2)
// clean but occupancy-capped, 259us. r11 (2,4) 1-col CLEAN (VGPR=68, WRITE
// 96KB) -> still 203us. Invariant: VALU-issue ~132-134us in EVERY variant
// -> the wall is VALU instruction count, not allocation.
// r12/r13: 2 cols/thread (r0's math, absmax 0.0, VGPR=112 proven at
// budget-256) under the (2,4) attribute: loads + all 36 product muls shared
// by 2 outputs -> ~139 VALU/output vs 180 (-23%), and 112 regs <= 128
// permits 4 waves/EU — the regime r0's launch_bounds(256,2) max-cap forbade.
// r13 = r12 resubmit (r12 died to container infra failure, not a counter
// result); constexpr-in-macro locals downgraded to const (identical
// semantics, literal indices) as the only hardening.
// c0 = 2*tid is even -> aligned float2 loads, NO parity weight vector:
// col0 taps G[j] on x[0..10], col1 taps G[j-1] on x[1..11] (bit-identical
// to r0). Immediate-consume per float2 pair keeps peak pressure low.

#define IMG 512
#define OUT_DIM 502    // 512 - 10 (VALID conv twice)
#define WIN 11
#define BH 32          // output rows per band
#define NPHASE (BH + WIN - 1)   // 42
#define NPLANES 96

#define GAUSS_INIT {0.00102838f, 0.00759875f, 0.03600077f, 0.10936071f, \
                    0.21300553f, 0.26601172f, 0.21300553f, 0.10936071f, \
                    0.03600077f, 0.00759875f, 0.00102838f}

template<int PH>
__device__ __forceinline__ void phase_step(
    int base, int r0row, int c0, int cbase,
    const float* __restrict__ Xp, const float* __restrict__ Yp,
    float (&a)[5][2][WIN], float& local) {
    constexpr float G[WIN] = GAUSS_INIT;   // matches numpy fp32 (absmax 0.0)
    const int p = base + PH;
    if (p >= NPHASE) return;               // uniform; only last outer iter
    const int rr = min(r0row + p, IMG - 1);  // clamped rows feed only discarded outputs
    const float* px = Xp + rr * IMG + cbase;
    const float* py = Yp + rr * IMG + cbase;

    // Horizontal blur for BOTH cols. Element j (cols cbase+j, j=0..11):
    // products computed ONCE, col0 accumulates G[j] (j<=10), col1 G[j-1]
    // (j>=1). Ascending-j chain order == r0's proven bit-exact order.
    float h0a = 0.f, h1a = 0.f, h2a = 0.f, h3a = 0.f, h4a = 0.f;
    float h0b = 0.f, h1b = 0.f, h2b = 0.f, h3b = 0.f, h4b = 0.f;
#define ELT(j, xe, ye) do {                                       \
        const float xx = (xe) * (xe);                             \
        const float yy = (ye) * (ye);                             \
        const float xy = (xe) * (ye);                             \
        if ((j) <= 10) {                                          \
            const float ga = G[(j) <= 10 ? (j) : 0];              \
            h0a = fmaf(ga, (xe), h0a);                            \
            h1a = fmaf(ga, (ye), h1a);                            \
            h2a = fmaf(ga, xx, h2a);                              \
            h3a = fmaf(ga, yy, h3a);                              \
            h4a = fmaf(ga, xy, h4a);                              \
        }                                                         \
        if ((j) >= 1) {                                           \
            const float gb = G[(j) >= 1 ? (j) - 1 : 0];           \
            h0b = fmaf(gb, (xe), h0b);                            \
            h1b = fmaf(gb, (ye), h1b);                            \
            h2b = fmaf(gb, xx, h2b);                              \
            h3b = fmaf(gb, yy, h3b);                              \
            h4b = fmaf(gb, xy, h4b);                              \
        }                                                         \
    } while (0)
#define PAIR(i) do {                                              \
        const float2 xv = *(const float2*)(px + 2 * (i));         \
        const float2 yv = *(const float2*)(py + 2 * (i));         \
        ELT(2 * (i),     xv.x, yv.x);                             \
        ELT(2 * (i) + 1, xv.y, yv.y);                             \
    } while (0)
    PAIR(0); PAIR(1); PAIR(2); PAIR(3); PAIR(4); PAIR(5);
#undef PAIR
#undef ELT

    // Row r contributes weight G[d] to output row r-d; slot (p-d) mod 11.
    // d==0 ASSIGNS its slot (freed by last phase's emit) -> no init/reset.
#define ACC(d) do {                                               \
        const int s = (PH - (d) + 2 * WIN) % WIN;                 \
        const float g = G[(d)];                                   \
        if ((d) == 0) {                                           \
            a[0][0][s] = g * h0a; a[1][0][s] = g * h1a;           \
            a[2][0][s] = g * h2a; a[3][0][s] = g * h3a;           \
            a[4][0][s] = g * h4a;                                 \
            a[0][1][s] = g * h0b; a[1][1][s] = g * h1b;           \
            a[2][1][s] = g * h2b; a[3][1][s] = g * h3b;           \
            a[4][1][s] = g * h4b;                                 \
        } else {                                                  \
            a[0][0][s] = fmaf(g, h0a, a[0][0][s]);                \
            a[1][0][s] = fmaf(g, h1a, a[1][0][s]);                \
            a[2][0][s] = fmaf(g, h2a, a[2][0][s]);                \
            a[3][0][s] = fmaf(g, h3a, a[3][0][s]);                \
            a[4][0][s] = fmaf(g, h4a, a[4][0][s]);                \
            a[0][1][s] = fmaf(g, h0b, a[0][1][s]);                \
            a[1][1][s] = fmaf(g, h1b, a[1][1][s]);                \
            a[2][1][s] = fmaf(g, h2b, a[2][1][s]);                \
            a[3][1][s] = fmaf(g, h3b, a[3][1][s]);                \
            a[4][1][s] = fmaf(g, h4b, a[4][1][s]);                \
        }                                                         \
    } while (0)
    ACC(0); ACC(1); ACC(2); ACC(3); ACC(4); ACC(5);
    ACC(6); ACC(7); ACC(8); ACC(9); ACC(10);
#undef ACC

    // Output row o = r-10 completed this phase; its slot is (PH+1)%11.
    if (p >= WIN - 1) {
        const int o = r0row + p - (WIN - 1);
        if (o < OUT_DIM && c0 < OUT_DIM) {   // c0 even: c0<502 covers both cols
            const int se = (PH + 1) % WIN;
            const float C1 = 0.0001f, C2 = 0.0009f;
            #pragma unroll
            for (int cc = 0; cc < 2; ++cc) {
                const float m1 = a[0][cc][se], m2 = a[1][cc][se];
                const float m1sq = m1 * m1, m2sq = m2 * m2, m12 = m1 * m2;
                const float s1  = a[2][cc][se] - m1sq;
                const float s2  = a[3][cc][se] - m2sq;
                const float s12 = a[4][cc][se] - m12;
                const float num = (2.f * m12 + C1) * (2.f * s12 + C2);
                const float den = (m1sq + m2sq + C1) * (s1 + s2 + C2);
                local += num * __builtin_amdgcn_rcpf(den);
            }
        }
    }
}

__global__ __launch_bounds__(256)
__attribute__((amdgpu_waves_per_eu(2, 4)))   // budget from min=2 (no spill); max=4 allows 4 waves/EU
void ssim_stream(const float* __restrict__ X,
                 const float* __restrict__ Y,
                 float* __restrict__ planeSums) {
    const int tid = threadIdx.x;
    const int r0row = blockIdx.x * BH;
    const int plane = blockIdx.y;
    const size_t pbase = (size_t)plane * IMG * IMG;
    const float* Xp = X + pbase;
    const float* Yp = Y + pbase;
    const int c0 = tid << 1;                  // this lane's 2 output cols (even)
    const int cbase = min(c0, IMG - 12);      // clamp: loads stay in-bounds;
                                              // clamped lanes never emit

    float a[5][2][WIN];                       // 110 regs once SROA'd (r0: VGPR=112)
    float local = 0.f;

    for (int base = 0; base < 44; base += WIN) {  // 4 x 11 phases, guard trims to 42
        phase_step<0>(base, r0row, c0, cbase, Xp, Yp, a, local);
        phase_step<1>(base, r0row, c0, cbase, Xp, Yp, a, local);
        phase_step<2>(base, r0row, c0, cbase, Xp, Yp, a, local);
        phase_step<3>(base, r0row, c0, cbase, Xp, Yp, a, local);
        phase_step<4>(base, r0row, c0, cbase, Xp, Yp, a, local);
        phase_step<5>(base, r0row, c0, cbase, Xp, Yp, a, local);
        phase_step<6>(base, r0row, c0, cbase, Xp, Yp, a, local);
        phase_step<7>(base, r0row, c0, cbase, Xp, Yp, a, local);
        phase_step<8>(base, r0row, c0, cbase, Xp, Yp, a, local);
        phase_step<9>(base, r0row, c0, cbase, Xp, Yp, a, local);
        phase_step<10>(base, r0row, c0, cbase, Xp, Yp, a, local);
    }

    // Block reduction -> one atomic per block (16 blocks/plane).
    #pragma unroll
    for (int off = 32; off > 0; off >>= 1)
        local += __shfl_down(local, off, 64);
    __shared__ float red[4];
    if ((tid & 63) == 0) red[tid >> 6] = local;
    __syncthreads();
    if (tid == 0)
        atomicAdd(&planeSums[plane], (red[0] + red[1]) + (red[2] + red[3]));
}

__global__ __launch_bounds__(128) void ssim_finalize(const float* __restrict__ planeSums,
                                                     float* __restrict__ out) {
    const int tid = threadIdx.x;
    float v = 0.f;
    if (tid < NPLANES) {
        const float m = planeSums[tid] * (1.0f / (float)(OUT_DIM * OUT_DIM));
        v = fmaxf(m, 0.f);   // nonnegative_ssim relu
    }
    #pragma unroll
    for (int off = 32; off > 0; off >>= 1)
        v += __shfl_down(v, off, 64);
    __shared__ float red[2];
    if ((tid & 63) == 0) red[tid >> 6] = v;
    __syncthreads();
    if (tid == 0) out[0] = 1.0f - (red[0] + red[1]) * (1.0f / (float)NPLANES);
}

extern "C" void kernel_launch(void* const* d_in, const int* in_sizes, int n_in,
                              void* d_out, int out_size, void* d_ws, size_t ws_size,
                              hipStream_t stream) {
    const float* X = (const float*)d_in[0];   // predictions
    const float* Y = (const float*)d_in[1];   // labels
    float* out = (float*)d_out;
    float* ws  = (float*)d_ws;                // 96 per-plane sums

    hipMemsetAsync(ws, 0, NPLANES * sizeof(float), stream);

    dim3 grid((OUT_DIM + BH - 1) / BH, NPLANES);   // 16 x 96 = 1536 blocks
    ssim_stream<<<grid, 256, 0, stream>>>(X, Y, ws);
    ssim_finalize<<<1, 128, 0, stream>>>(ws, out);
}

// Round 10
// 324.485 us; speedup vs baseline: 1.1125x; 1.1125x over previous
//
#include <hip/hip_runtime.h>

// SSIM loss, streaming-row kernel, no LDS in the hot loop, no barriers.
// Empirical law fitted over r0-r13 (8 data points): achieved waves/EU =
// floor(512 / (2 x arch VGPR)) capped by attr max — toolchain reserves an
// AGPR shadow equal to arch count. r13's 2-col body (VGPR=112, VALU-issue
// 90us, -32% vs 1-col) is locked to 2 waves/EU by its 110-reg ring -> 231us.
// r11's 1-col body was 68 regs = 56 + 12-reg parity weight vector W ->
// 3 waves -> 203us. r14: drop W entirely by replacing the 12 aligned
// float2 loads with 22 scalar dword loads (lane c loads px[k], k literal):
//   - perfectly coalesced (consecutive lanes -> consecutive addresses)
//   - zero VALU cost, no parity select, no alignment constraint
//   - bit-identical: odd lanes' old path was fmaf(0,.,h) + ascending
//     G[k]*x[c+k]; new path is the same ascending chain (absmax 0.0 kept)
// Target: arch ~56 -> 2x56=112 -> 4 waves/EU clean under (2,4).
// Ring: 5 maps x 11 rolling vertical accumulators, d==0 assigns its slot.

#define IMG 512
#define OUT_DIM 502    // 512 - 10 (VALID conv twice)
#define WIN 11
#define BH 32          // output rows per band
#define NPHASE (BH + WIN - 1)   // 42
#define NPLANES 96

#define GAUSS_INIT {0.00102838f, 0.00759875f, 0.03600077f, 0.10936071f, \
                    0.21300553f, 0.26601172f, 0.21300553f, 0.10936071f, \
                    0.03600077f, 0.00759875f, 0.00102838f}

template<int PH>
__device__ __forceinline__ void phase_step(
    int base, int r0row, int c, int cbase,
    const float* __restrict__ Xp, const float* __restrict__ Yp,
    float (&a)[5][WIN], float& local) {
    constexpr float G[WIN] = GAUSS_INIT;   // matches numpy fp32 (absmax 0.0)
    const int p = base + PH;
    if (p >= NPHASE) return;               // uniform; only last outer iter
    const int rr = min(r0row + p, IMG - 1);  // clamped rows feed only discarded outputs
    const float* px = Xp + rr * IMG + cbase;
    const float* py = Yp + rr * IMG + cbase;

    // Horizontal blur, 11 taps, uniform weights (SGPR-resident constants).
    // Scalar dword loads, literal offsets, immediate-consume per tap so the
    // raw values die fast. Ascending-k chain = proven bit-exact order.
    float h0 = 0.f, h1 = 0.f, h2 = 0.f, h3 = 0.f, h4 = 0.f;
#define KSTEP(k) do {                                             \
        const float xk = px[(k)];                                 \
        const float yk = py[(k)];                                 \
        h0 = fmaf(G[(k)], xk, h0);                                \
        h1 = fmaf(G[(k)], yk, h1);                                \
        h2 = fmaf(G[(k)], xk * xk, h2);                           \
        h3 = fmaf(G[(k)], yk * yk, h3);                           \
        h4 = fmaf(G[(k)], xk * yk, h4);                           \
    } while (0)
    KSTEP(0); KSTEP(1); KSTEP(2); KSTEP(3); KSTEP(4); KSTEP(5);
    KSTEP(6); KSTEP(7); KSTEP(8); KSTEP(9); KSTEP(10);
#undef KSTEP

    // Row r contributes weight G[d] to output row r-d; slot (p-d) mod 11.
    // d==0 ASSIGNS its slot (freed by last phase's emit) -> no init/reset.
#define ACC(d) do {                                               \
        const int s = (PH - (d) + 2 * WIN) % WIN;                 \
        const float g = G[(d)];                                   \
        if ((d) == 0) {                                           \
            a[0][s] = g * h0; a[1][s] = g * h1; a[2][s] = g * h2; \
            a[3][s] = g * h3; a[4][s] = g * h4;                   \
        } else {                                                  \
            a[0][s] = fmaf(g, h0, a[0][s]);                       \
            a[1][s] = fmaf(g, h1, a[1][s]);                       \
            a[2][s] = fmaf(g, h2, a[2][s]);                       \
            a[3][s] = fmaf(g, h3, a[3][s]);                       \
            a[4][s] = fmaf(g, h4, a[4][s]);                       \
        }                                                         \
    } while (0)
    ACC(0); ACC(1); ACC(2); ACC(3); ACC(4); ACC(5);
    ACC(6); ACC(7); ACC(8); ACC(9); ACC(10);
#undef ACC

    // Output row o = r-10 completed this phase; its slot is (PH+1)%11.
    if (p >= WIN - 1) {
        const int o = r0row + p - (WIN - 1);
        if (o < OUT_DIM && c < OUT_DIM) {
            const int se = (PH + 1) % WIN;
            const float C1 = 0.0001f, C2 = 0.0009f;
            const float m1 = a[0][se], m2 = a[1][se];
            const float m1sq = m1 * m1, m2sq = m2 * m2, m12 = m1 * m2;
            const float s1  = a[2][se] - m1sq;
            const float s2  = a[3][se] - m2sq;
            const float s12 = a[4][se] - m12;
            const float num = (2.f * m12 + C1) * (2.f * s12 + C2);
            const float den = (m1sq + m2sq + C1) * (s1 + s2 + C2);
            local += num * __builtin_amdgcn_rcpf(den);
        }
    }
}

__global__ __launch_bounds__(256)
__attribute__((amdgpu_waves_per_eu(2, 4)))   // budget from min=2 (no spill); max=4
void ssim_stream(const float* __restrict__ X,
                 const float* __restrict__ Y,
                 float* __restrict__ planeSums) {
    const int tid = threadIdx.x;
    const int r0row = blockIdx.x * BH;
    const int c = (blockIdx.y << 8) + tid;    // this lane's single output col
    const int plane = blockIdx.z;
    const size_t pbase = (size_t)plane * IMG * IMG;
    const float* Xp = X + pbase;
    const float* Yp = Y + pbase;
    const int cbase = min(c, IMG - WIN);      // window start; clamp keeps loads
                                              // in-bounds, clamped lanes never emit

    float a[5][WIN];                          // 55 ring regs + ~1 local + temps
    float local = 0.f;

    for (int base = 0; base < 44; base += WIN) {  // 4 x 11 phases, guard trims to 42
        phase_step<0>(base, r0row, c, cbase, Xp, Yp, a, local);
        phase_step<1>(base, r0row, c, cbase, Xp, Yp, a, local);
        phase_step<2>(base, r0row, c, cbase, Xp, Yp, a, local);
        phase_step<3>(base, r0row, c, cbase, Xp, Yp, a, local);
        phase_step<4>(base, r0row, c, cbase, Xp, Yp, a, local);
        phase_step<5>(base, r0row, c, cbase, Xp, Yp, a, local);
        phase_step<6>(base, r0row, c, cbase, Xp, Yp, a, local);
        phase_step<7>(base, r0row, c, cbase, Xp, Yp, a, local);
        phase_step<8>(base, r0row, c, cbase, Xp, Yp, a, local);
        phase_step<9>(base, r0row, c, cbase, Xp, Yp, a, local);
        phase_step<10>(base, r0row, c, cbase, Xp, Yp, a, local);
    }

    // Block reduction -> one atomic per block (32 blocks/plane).
    #pragma unroll
    for (int off = 32; off > 0; off >>= 1)
        local += __shfl_down(local, off, 64);
    __shared__ float red[4];
    if ((tid & 63) == 0) red[tid >> 6] = local;
    __syncthreads();
    if (tid == 0)
        atomicAdd(&planeSums[plane], (red[0] + red[1]) + (red[2] + red[3]));
}

__global__ __launch_bounds__(128) void ssim_finalize(const float* __restrict__ planeSums,
                                                     float* __restrict__ out) {
    const int tid = threadIdx.x;
    float v = 0.f;
    if (tid < NPLANES) {
        const float m = planeSums[tid] * (1.0f / (float)(OUT_DIM * OUT_DIM));
        v = fmaxf(m, 0.f);   // nonnegative_ssim relu
    }
    #pragma unroll
    for (int off = 32; off > 0; off >>= 1)
        v += __shfl_down(v, off, 64);
    __shared__ float red[2];
    if ((tid & 63) == 0) red[tid >> 6] = v;
    __syncthreads();
    if (tid == 0) out[0] = 1.0f - (red[0] + red[1]) * (1.0f / (float)NPLANES);
}

extern "C" void kernel_launch(void* const* d_in, const int* in_sizes, int n_in,
                              void* d_out, int out_size, void* d_ws, size_t ws_size,
                              hipStream_t stream) {
    const float* X = (const float*)d_in[0];   // predictions
    const float* Y = (const float*)d_in[1];   // labels
    float* out = (float*)d_out;
    float* ws  = (float*)d_ws;                // 96 per-plane sums

    hipMemsetAsync(ws, 0, NPLANES * sizeof(float), stream);

    dim3 grid((OUT_DIM + BH - 1) / BH, 2, NPLANES);   // 16 x 2 x 96 = 3072 blocks
    ssim_stream<<<grid, 256, 0, stream>>>(X, Y, ws);
    ssim_finalize<<<1, 128, 0, stream>>>(ws, out);
}

// Round 11
// 299.872 us; speedup vs baseline: 1.2038x; 1.0821x over previous
//
#include <hip/hip_runtime.h>

// SSIM loss, streaming-row kernel, no LDS in the hot loop, no barriers.
// State after r14: 1 col/thread, scalar dword loads (no W vector), clean
// codegen (VGPR=68, WRITE 96KB), (2,4) attr -> ~3 waves/EU, 195us.
// VALU-issue invariant ~129us; 68 regs sits in the 128-granule (waves
// halve at 64/128/256) and the allocator refuses to go below 68, so the
// occupancy fight is parked.
// r15: cut WORK instead. Band warm-up costs WIN-1=10 phases per band
// regardless of BH. BH 32 -> 128: per-col phases 16x42=672 -> 4x138=552
// (0.82x), ring/regs/per-phase code UNCHANGED. Grid 4x2x96 = 768 blocks
// = exactly 3 blocks/CU = one perfectly-packed round at the observed
// 3-block occupancy (no tail).
// Math unchanged (absmax 0.0 r14): ascending-k 11-tap Gaussian chain,
// 11-slot rolling vertical ring, d==0 assigns its slot.

#define IMG 512
#define OUT_DIM 502    // 512 - 10 (VALID conv twice)
#define WIN 11
#define BH 128         // output rows per band (r15: was 32)
#define NPHASE (BH + WIN - 1)   // 138
#define NPLANES 96

#define GAUSS_INIT {0.00102838f, 0.00759875f, 0.03600077f, 0.10936071f, \
                    0.21300553f, 0.26601172f, 0.21300553f, 0.10936071f, \
                    0.03600077f, 0.00759875f, 0.00102838f}

template<int PH>
__device__ __forceinline__ void phase_step(
    int base, int r0row, int c, int cbase,
    const float* __restrict__ Xp, const float* __restrict__ Yp,
    float (&a)[5][WIN], float& local) {
    constexpr float G[WIN] = GAUSS_INIT;   // matches numpy fp32 (absmax 0.0)
    const int p = base + PH;
    if (p >= NPHASE) return;               // uniform; only last outer iter
    const int rr = min(r0row + p, IMG - 1);  // clamped rows feed only discarded outputs
    const float* px = Xp + rr * IMG + cbase;
    const float* py = Yp + rr * IMG + cbase;

    // Horizontal blur, 11 taps, uniform weights (SGPR-resident constants).
    // Scalar dword loads, literal offsets, immediate-consume per tap so the
    // raw values die fast. Ascending-k chain = proven bit-exact order.
    float h0 = 0.f, h1 = 0.f, h2 = 0.f, h3 = 0.f, h4 = 0.f;
#define KSTEP(k) do {                                             \
        const float xk = px[(k)];                                 \
        const float yk = py[(k)];                                 \
        h0 = fmaf(G[(k)], xk, h0);                                \
        h1 = fmaf(G[(k)], yk, h1);                                \
        h2 = fmaf(G[(k)], xk * xk, h2);                           \
        h3 = fmaf(G[(k)], yk * yk, h3);                           \
        h4 = fmaf(G[(k)], xk * yk, h4);                           \
    } while (0)
    KSTEP(0); KSTEP(1); KSTEP(2); KSTEP(3); KSTEP(4); KSTEP(5);
    KSTEP(6); KSTEP(7); KSTEP(8); KSTEP(9); KSTEP(10);
#undef KSTEP

    // Row r contributes weight G[d] to output row r-d; slot (p-d) mod 11.
    // d==0 ASSIGNS its slot (freed by last phase's emit) -> no init/reset.
#define ACC(d) do {                                               \
        const int s = (PH - (d) + 2 * WIN) % WIN;                 \
        const float g = G[(d)];                                   \
        if ((d) == 0) {                                           \
            a[0][s] = g * h0; a[1][s] = g * h1; a[2][s] = g * h2; \
            a[3][s] = g * h3; a[4][s] = g * h4;                   \
        } else {                                                  \
            a[0][s] = fmaf(g, h0, a[0][s]);                       \
            a[1][s] = fmaf(g, h1, a[1][s]);                       \
            a[2][s] = fmaf(g, h2, a[2][s]);                       \
            a[3][s] = fmaf(g, h3, a[3][s]);                       \
            a[4][s] = fmaf(g, h4, a[4][s]);                       \
        }                                                         \
    } while (0)
    ACC(0); ACC(1); ACC(2); ACC(3); ACC(4); ACC(5);
    ACC(6); ACC(7); ACC(8); ACC(9); ACC(10);
#undef ACC

    // Output row o = r-10 completed this phase; its slot is (PH+1)%11.
    if (p >= WIN - 1) {
        const int o = r0row + p - (WIN - 1);
        if (o < OUT_DIM && c < OUT_DIM) {
            const int se = (PH + 1) % WIN;
            const float C1 = 0.0001f, C2 = 0.0009f;
            const float m1 = a[0][se], m2 = a[1][se];
            const float m1sq = m1 * m1, m2sq = m2 * m2, m12 = m1 * m2;
            const float s1  = a[2][se] - m1sq;
            const float s2  = a[3][se] - m2sq;
            const float s12 = a[4][se] - m12;
            const float num = (2.f * m12 + C1) * (2.f * s12 + C2);
            const float den = (m1sq + m2sq + C1) * (s1 + s2 + C2);
            local += num * __builtin_amdgcn_rcpf(den);
        }
    }
}

__global__ __launch_bounds__(256)
__attribute__((amdgpu_waves_per_eu(2, 4)))   // budget from min=2 (no spill); max=4
void ssim_stream(const float* __restrict__ X,
                 const float* __restrict__ Y,
                 float* __restrict__ planeSums) {
    const int tid = threadIdx.x;
    const int r0row = blockIdx.x * BH;
    const int c = (blockIdx.y << 8) + tid;    // this lane's single output col
    const int plane = blockIdx.z;
    const size_t pbase = (size_t)plane * IMG * IMG;
    const float* Xp = X + pbase;
    const float* Yp = Y + pbase;
    const int cbase = min(c, IMG - WIN);      // window start; clamp keeps loads
                                              // in-bounds, clamped lanes never emit

    float a[5][WIN];                          // 55 ring regs + ~1 local + temps
    float local = 0.f;

    // 13 x 11 = 143 phase slots; guard trims to NPHASE=138.
    for (int base = 0; base < 143; base += WIN) {
        phase_step<0>(base, r0row, c, cbase, Xp, Yp, a, local);
        phase_step<1>(base, r0row, c, cbase, Xp, Yp, a, local);
        phase_step<2>(base, r0row, c, cbase, Xp, Yp, a, local);
        phase_step<3>(base, r0row, c, cbase, Xp, Yp, a, local);
        phase_step<4>(base, r0row, c, cbase, Xp, Yp, a, local);
        phase_step<5>(base, r0row, c, cbase, Xp, Yp, a, local);
        phase_step<6>(base, r0row, c, cbase, Xp, Yp, a, local);
        phase_step<7>(base, r0row, c, cbase, Xp, Yp, a, local);
        phase_step<8>(base, r0row, c, cbase, Xp, Yp, a, local);
        phase_step<9>(base, r0row, c, cbase, Xp, Yp, a, local);
        phase_step<10>(base, r0row, c, cbase, Xp, Yp, a, local);
    }

    // Block reduction -> one atomic per block (8 blocks/plane).
    #pragma unroll
    for (int off = 32; off > 0; off >>= 1)
        local += __shfl_down(local, off, 64);
    __shared__ float red[4];
    if ((tid & 63) == 0) red[tid >> 6] = local;
    __syncthreads();
    if (tid == 0)
        atomicAdd(&planeSums[plane], (red[0] + red[1]) + (red[2] + red[3]));
}

__global__ __launch_bounds__(128) void ssim_finalize(const float* __restrict__ planeSums,
                                                     float* __restrict__ out) {
    const int tid = threadIdx.x;
    float v = 0.f;
    if (tid < NPLANES) {
        const float m = planeSums[tid] * (1.0f / (float)(OUT_DIM * OUT_DIM));
        v = fmaxf(m, 0.f);   // nonnegative_ssim relu
    }
    #pragma unroll
    for (int off = 32; off > 0; off >>= 1)
        v += __shfl_down(v, off, 64);
    __shared__ float red[2];
    if ((tid & 63) == 0) red[tid >> 6] = v;
    __syncthreads();
    if (tid == 0) out[0] = 1.0f - (red[0] + red[1]) * (1.0f / (float)NPLANES);
}

extern "C" void kernel_launch(void* const* d_in, const int* in_sizes, int n_in,
                              void* d_out, int out_size, void* d_ws, size_t ws_size,
                              hipStream_t stream) {
    const float* X = (const float*)d_in[0];   // predictions
    const float* Y = (const float*)d_in[1];   // labels
    float* out = (float*)d_out;
    float* ws  = (float*)d_ws;                // 96 per-plane sums

    hipMemsetAsync(ws, 0, NPLANES * sizeof(float), stream);

    dim3 grid((OUT_DIM + BH - 1) / BH, 2, NPLANES);   // 4 x 2 x 96 = 768 blocks
    ssim_stream<<<grid, 256, 0, stream>>>(X, Y, ws);
    ssim_finalize<<<1, 128, 0, stream>>>(ws, out);
}